// Round 1
// baseline (451.461 us; speedup 1.0000x reference)
//
#include <hip/hip_runtime.h>
#include <math.h>

#define B_   256
#define D1_  512
#define T_   256
#define O1_  256
#define O2_  128
#define OT   32     // o-rows per block
#define DK   16     // k-chunk staged in LDS

// Fused: E = W1@x[b] (tile in LDS) -> S = E@W -> row softmax -> blended ->
// Y = blended@W2 + bias -> write to out (pre-softmax over O1).
__global__ __launch_bounds__(256) void tabl_fused(
    const float* __restrict__ x, const float* __restrict__ W1,
    const float* __restrict__ W, const float* __restrict__ W2,
    const float* __restrict__ alpha, const float* __restrict__ bias,
    float* __restrict__ out)
{
    __shared__ float Et[OT * T_];      // 32 KB: E tile, later blended (in place)
    __shared__ float ks[DK * T_];      // 16 KB: staging for x chunk / W chunk / W2 chunk
    __shared__ float w1s[DK * OT];     // 2 KB: W1 chunk, transposed [k][o]

    const int tid = threadIdx.x;
    const int tx = tid & 31;           // 0..31
    const int ty = tid >> 5;           // 0..7
    const int b = blockIdx.y;
    const int obase = blockIdx.x * OT;

    // ---------------- Stage 1: E[o][t] = sum_d W1[o][d] * x[b][d][t] ----------------
    float acc[4][8];
    #pragma unroll
    for (int i = 0; i < 4; ++i)
        #pragma unroll
        for (int j = 0; j < 8; ++j) acc[i][j] = 0.f;

    for (int d0 = 0; d0 < D1_; d0 += DK) {
        // stage x chunk: ks[k][t] = x[b][d0+k][t]   (DK x 256)
        const float4* x4 = (const float4*)(x + ((size_t)b * D1_ + d0) * T_);
        #pragma unroll
        for (int it = 0; it < 4; ++it) {
            int idx = it * 256 + tid;            // 0..1023 float4s
            int k = idx >> 6, tq = idx & 63;
            ((float4*)ks)[k * 64 + tq] = x4[k * 64 + tq];
        }
        // stage W1 chunk transposed: w1s[k][o] = W1[obase+o][d0+k]  (DK x 32)
        if (tid < 128) {
            int r = tid >> 2;                    // o 0..31
            int c = (tid & 3) * 4;               // k base
            float4 w = *(const float4*)(W1 + (size_t)(obase + r) * D1_ + d0 + c);
            w1s[(c + 0) * OT + r] = w.x;
            w1s[(c + 1) * OT + r] = w.y;
            w1s[(c + 2) * OT + r] = w.z;
            w1s[(c + 3) * OT + r] = w.w;
        }
        __syncthreads();
        #pragma unroll
        for (int k = 0; k < DK; ++k) {
            float4 a4 = *(const float4*)&w1s[k * OT + ty * 4];
            float4 b0 = *(const float4*)&ks[k * T_ + tx * 8];
            float4 b1 = *(const float4*)&ks[k * T_ + tx * 8 + 4];
            float ax[4] = {a4.x, a4.y, a4.z, a4.w};
            float bx[8] = {b0.x, b0.y, b0.z, b0.w, b1.x, b1.y, b1.z, b1.w};
            #pragma unroll
            for (int i = 0; i < 4; ++i)
                #pragma unroll
                for (int j = 0; j < 8; ++j)
                    acc[i][j] = fmaf(ax[i], bx[j], acc[i][j]);
        }
        __syncthreads();
    }
    // write E tile to LDS
    #pragma unroll
    for (int i = 0; i < 4; ++i) {
        float4 e0 = {acc[i][0], acc[i][1], acc[i][2], acc[i][3]};
        float4 e1 = {acc[i][4], acc[i][5], acc[i][6], acc[i][7]};
        *(float4*)&Et[(ty * 4 + i) * T_ + tx * 8]     = e0;
        *(float4*)&Et[(ty * 4 + i) * T_ + tx * 8 + 4] = e1;
    }
    __syncthreads();

    // ---------------- Stage 2: S[o][s] = sum_t E[o][t] * W[t][s] ----------------
    float s2a[4][8];
    #pragma unroll
    for (int i = 0; i < 4; ++i)
        #pragma unroll
        for (int j = 0; j < 8; ++j) s2a[i][j] = 0.f;

    for (int t0 = 0; t0 < T_; t0 += DK) {
        const float4* wch = (const float4*)(W + (size_t)t0 * T_);
        #pragma unroll
        for (int it = 0; it < 4; ++it) {
            int idx = it * 256 + tid;
            int k = idx >> 6, sq = idx & 63;
            ((float4*)ks)[k * 64 + sq] = wch[k * 64 + sq];
        }
        __syncthreads();
        #pragma unroll
        for (int k = 0; k < DK; ++k) {
            float e0 = Et[(ty * 4 + 0) * T_ + t0 + k];
            float e1 = Et[(ty * 4 + 1) * T_ + t0 + k];
            float e2 = Et[(ty * 4 + 2) * T_ + t0 + k];
            float e3 = Et[(ty * 4 + 3) * T_ + t0 + k];
            float4 b0 = *(const float4*)&ks[k * T_ + tx * 8];
            float4 b1 = *(const float4*)&ks[k * T_ + tx * 8 + 4];
            float ex[4] = {e0, e1, e2, e3};
            float bx[8] = {b0.x, b0.y, b0.z, b0.w, b1.x, b1.y, b1.z, b1.w};
            #pragma unroll
            for (int i = 0; i < 4; ++i)
                #pragma unroll
                for (int j = 0; j < 8; ++j)
                    s2a[i][j] = fmaf(ex[i], bx[j], s2a[i][j]);
        }
        __syncthreads();
    }

    // ---------------- row softmax over s + blended (in place into Et) ----------------
    const float a = alpha[0];
    #pragma unroll
    for (int i = 0; i < 4; ++i) {
        float m = -INFINITY;
        #pragma unroll
        for (int j = 0; j < 8; ++j) m = fmaxf(m, s2a[i][j]);
        #pragma unroll
        for (int msk = 16; msk >= 1; msk >>= 1) m = fmaxf(m, __shfl_xor(m, msk));
        float ssum = 0.f;
        #pragma unroll
        for (int j = 0; j < 8; ++j) { float p = __expf(s2a[i][j] - m); s2a[i][j] = p; ssum += p; }
        #pragma unroll
        for (int msk = 16; msk >= 1; msk >>= 1) ssum += __shfl_xor(ssum, msk);
        float inv = 1.f / ssum;
        // blended[o][s] = E[o][s] * (a + (1-a)*A[o][s]); in-place (own elements only)
        #pragma unroll
        for (int jq = 0; jq < 2; ++jq) {
            float4 e = *(const float4*)&Et[(ty * 4 + i) * T_ + tx * 8 + jq * 4];
            float A0 = s2a[i][jq * 4 + 0] * inv;
            float A1 = s2a[i][jq * 4 + 1] * inv;
            float A2 = s2a[i][jq * 4 + 2] * inv;
            float A3 = s2a[i][jq * 4 + 3] * inv;
            float4 r;
            r.x = e.x * (a + (1.f - a) * A0);
            r.y = e.y * (a + (1.f - a) * A1);
            r.z = e.z * (a + (1.f - a) * A2);
            r.w = e.w * (a + (1.f - a) * A3);
            *(float4*)&Et[(ty * 4 + i) * T_ + tx * 8 + jq * 4] = r;
        }
    }
    __syncthreads();

    // ---------------- Stage 3: Y[o][s2] = sum_t blended[o][t] * W2[t][s2] + bias ----------------
    float y[4][4];
    #pragma unroll
    for (int i = 0; i < 4; ++i)
        #pragma unroll
        for (int q = 0; q < 4; ++q) y[i][q] = 0.f;

    for (int t0 = 0; t0 < T_; t0 += DK) {
        const float4* w24 = (const float4*)(W2 + (size_t)t0 * O2_);
        #pragma unroll
        for (int it = 0; it < 2; ++it) {
            int idx = it * 256 + tid;            // 0..511 float4s
            int k = idx >> 5, sq = idx & 31;
            ((float4*)ks)[k * 32 + sq] = w24[k * 32 + sq];
        }
        __syncthreads();
        #pragma unroll
        for (int k = 0; k < DK; ++k) {
            float e0 = Et[(ty * 4 + 0) * T_ + t0 + k];
            float e1 = Et[(ty * 4 + 1) * T_ + t0 + k];
            float e2 = Et[(ty * 4 + 2) * T_ + t0 + k];
            float e3 = Et[(ty * 4 + 3) * T_ + t0 + k];
            float4 w4 = *(const float4*)&ks[k * O2_ + tx * 4];
            float ex[4] = {e0, e1, e2, e3};
            float wx[4] = {w4.x, w4.y, w4.z, w4.w};
            #pragma unroll
            for (int i = 0; i < 4; ++i)
                #pragma unroll
                for (int q = 0; q < 4; ++q)
                    y[i][q] = fmaf(ex[i], wx[q], y[i][q]);
        }
        __syncthreads();
    }

    // epilogue: add bias, store Y (pre final softmax)
    #pragma unroll
    for (int i = 0; i < 4; ++i) {
        int o = obase + ty * 4 + i;
        float4 bb = *(const float4*)&bias[(size_t)o * O2_ + tx * 4];
        float4 o4 = {y[i][0] + bb.x, y[i][1] + bb.y, y[i][2] + bb.z, y[i][3] + bb.w};
        *(float4*)&out[((size_t)b * O1_ + o) * O2_ + tx * 4] = o4;
    }
}

// In-place softmax over axis 1 (O1) of out[B][O1][O2]. One thread per (b, s2).
__global__ __launch_bounds__(256) void softmax_axis1(float* __restrict__ out)
{
    int col = blockIdx.x * blockDim.x + threadIdx.x;   // 0 .. B*O2-1
    int b = col >> 7;            // /O2_
    int s2 = col & (O2_ - 1);
    float* p = out + (size_t)b * O1_ * O2_ + s2;
    float m = -INFINITY, s = 0.f;
    for (int o = 0; o < O1_; ++o) {
        float v = p[o * O2_];
        float mn = fmaxf(m, v);
        s = s * __expf(m - mn) + __expf(v - mn);
        m = mn;
    }
    float inv = 1.f / s;
    for (int o = 0; o < O1_; ++o) {
        float v = p[o * O2_];
        p[o * O2_] = __expf(v - m) * inv;
    }
}

extern "C" void kernel_launch(void* const* d_in, const int* in_sizes, int n_in,
                              void* d_out, int out_size, void* d_ws, size_t ws_size,
                              hipStream_t stream)
{
    const float* x     = (const float*)d_in[0];
    const float* W1    = (const float*)d_in[1];
    const float* W     = (const float*)d_in[2];
    const float* W2    = (const float*)d_in[3];
    const float* alpha = (const float*)d_in[4];
    const float* bias  = (const float*)d_in[5];
    float* out = (float*)d_out;

    dim3 gridA(O1_ / OT, B_);
    tabl_fused<<<gridA, 256, 0, stream>>>(x, W1, W, W2, alpha, bias, out);
    softmax_axis1<<<(B_ * O2_) / 256, 256, 0, stream>>>(out);
}

// Round 2
// 193.207 us; speedup vs baseline: 2.3367x; 2.3367x over previous
//
#include <hip/hip_runtime.h>
#include <hip/hip_bf16.h>
#include <math.h>

#define B_   256
#define D1_  512
#define T_   256
#define O1_  256
#define O2_  128

typedef __attribute__((ext_vector_type(8))) short bf16x8;
typedef __attribute__((ext_vector_type(4))) float f32x4;

// pack two floats -> two bf16 (RNE), returned as u32 (low half = a)
__device__ inline unsigned pk2(float a, float b) {
    __hip_bfloat162 h = __float22bfloat162_rn(make_float2(a, b));
    union { __hip_bfloat162 h; unsigned u; } c;
    c.h = h;
    return c.u;
}

// split 4 floats into hi-plane (2 packed u32) and lo-plane
__device__ inline void split4(float v0, float v1, float v2, float v3,
                              uint2& hp, uint2& lp) {
    unsigned h01 = pk2(v0, v1), h23 = pk2(v2, v3);
    float r0 = v0 - __uint_as_float(h01 << 16);
    float r1 = v1 - __uint_as_float(h01 & 0xFFFF0000u);
    float r2 = v2 - __uint_as_float(h23 << 16);
    float r3 = v3 - __uint_as_float(h23 & 0xFFFF0000u);
    hp.x = h01; hp.y = h23;
    lp.x = pk2(r0, r1); lp.y = pk2(r2, r3);
}

// fragment load from 72-byte-strided staging rows (two ds_read_b64)
__device__ inline bf16x8 ld72(const char* base, int row, int k0) {
    const char* p = base + row * 72 + 2 * k0;
    union { uint2 a[2]; bf16x8 v; } f;
    f.a[0] = *(const uint2*)p;
    f.a[1] = *(const uint2*)(p + 8);
    return f.v;
}

// fragment load from E planes (512-B rows, XOR-swizzled 16B slots)
__device__ inline bf16x8 ldE(const char* base, int row, int t0) {
    return *(const bf16x8*)(base + row * 512 + ((2 * t0) ^ ((row & 7) << 4)));
}
__device__ inline int eoff(int row, int t) {
    return row * 512 + ((2 * t) ^ ((row & 7) << 4));
}

#define MFMA16 __builtin_amdgcn_mfma_f32_16x16x32_bf16

__global__ __launch_bounds__(512, 2) void tabl_mfma(
    const float* __restrict__ x, const float* __restrict__ W1,
    const float* __restrict__ W, const float* __restrict__ W2,
    const float* __restrict__ alpha, const float* __restrict__ bias,
    float* __restrict__ out)
{
    __shared__ __align__(16) char Eh[64 * 512];       // E-hi, later blended-hi
    __shared__ __align__(16) char El[64 * 512];       // blended-lo
    __shared__ __align__(16) char Bst[2][256 * 72];   // B-operand staging hi/lo
    __shared__ __align__(16) char Ast[2][64 * 72];    // A-operand (W1) staging hi/lo
    __shared__ float redm[4][64];
    __shared__ float reds[4][64];

    const int tid    = threadIdx.x;
    const int lane   = tid & 63;
    const int lane16 = lane & 15;
    const int lg     = lane >> 4;     // 0..3
    const int wid    = tid >> 6;      // 0..7
    const int wm     = wid >> 2;      // 0..1
    const int wn     = wid & 3;       // 0..3
    const int rowW   = wm * 32;
    const int colW   = wn * 64;
    const int b      = blockIdx.y;
    const int obase  = blockIdx.x * 64;

    // staging roles (256-wide transpose stagers)
    const int xs_t  = tid & 255;
    const int xs_kh = tid >> 8;       // 0/1 (k-half)

    // ================= Stage 1: E = W1 @ x[b]  (3-term hi/lo) =================
    f32x4 Eacc[2][4];
    #pragma unroll
    for (int mt = 0; mt < 2; ++mt)
        #pragma unroll
        for (int nt = 0; nt < 4; ++nt)
            Eacc[mt][nt] = (f32x4){0.f, 0.f, 0.f, 0.f};

    const float* xsrc = x + ((size_t)b * D1_) * T_ + xs_t;
    const int w1r = tid >> 3, w1k = tid & 7;

    float xa[16]; float4 wa;
    #pragma unroll
    for (int j = 0; j < 16; ++j) xa[j] = xsrc[(size_t)(xs_kh * 16 + j) * T_];
    wa = *(const float4*)(W1 + (size_t)(obase + w1r) * D1_ + w1k * 4);

    #pragma unroll 2
    for (int c = 0; c < 16; ++c) {
        float xb2[16]; float4 wb2;
        if (c < 15) {
            #pragma unroll
            for (int j = 0; j < 16; ++j)
                xb2[j] = xsrc[(size_t)((c + 1) * 32 + xs_kh * 16 + j) * T_];
            wb2 = *(const float4*)(W1 + (size_t)(obase + w1r) * D1_ + (c + 1) * 32 + w1k * 4);
        }
        // convert + transposed write of current chunk
        {
            char* bh = Bst[0] + xs_t * 72 + xs_kh * 32;
            char* bl = Bst[1] + xs_t * 72 + xs_kh * 32;
            #pragma unroll
            for (int q = 0; q < 4; ++q) {
                uint2 hp, lp;
                split4(xa[q*4+0], xa[q*4+1], xa[q*4+2], xa[q*4+3], hp, lp);
                *(uint2*)(bh + q * 8) = hp;
                *(uint2*)(bl + q * 8) = lp;
            }
            uint2 hp, lp;
            split4(wa.x, wa.y, wa.z, wa.w, hp, lp);
            *(uint2*)(Ast[0] + w1r * 72 + w1k * 8) = hp;
            *(uint2*)(Ast[1] + w1r * 72 + w1k * 8) = lp;
        }
        __syncthreads();
        {
            bf16x8 Ah[2], Al[2], Bh[4], Bl[4];
            #pragma unroll
            for (int mt = 0; mt < 2; ++mt) {
                int r = rowW + mt * 16 + lane16;
                Ah[mt] = ld72(Ast[0], r, lg * 8);
                Al[mt] = ld72(Ast[1], r, lg * 8);
            }
            #pragma unroll
            for (int nt = 0; nt < 4; ++nt) {
                int n = colW + nt * 16 + lane16;
                Bh[nt] = ld72(Bst[0], n, lg * 8);
                Bl[nt] = ld72(Bst[1], n, lg * 8);
            }
            #pragma unroll
            for (int mt = 0; mt < 2; ++mt)
                #pragma unroll
                for (int nt = 0; nt < 4; ++nt) {
                    Eacc[mt][nt] = MFMA16(Ah[mt], Bh[nt], Eacc[mt][nt], 0, 0, 0);
                    Eacc[mt][nt] = MFMA16(Ah[mt], Bl[nt], Eacc[mt][nt], 0, 0, 0);
                    Eacc[mt][nt] = MFMA16(Al[mt], Bh[nt], Eacc[mt][nt], 0, 0, 0);
                }
        }
        __syncthreads();
        if (c < 15) {
            #pragma unroll
            for (int j = 0; j < 16; ++j) xa[j] = xb2[j];
            wa = wb2;
        }
    }

    // write E-hi to LDS for stage-2 A fragments (E itself stays in regs)
    #pragma unroll
    for (int mt = 0; mt < 2; ++mt)
        #pragma unroll
        for (int nt = 0; nt < 4; ++nt)
            #pragma unroll
            for (int i = 0; i < 4; ++i) {
                int r = rowW + mt * 16 + lg * 4 + i;
                int t = colW + nt * 16 + lane16;
                float v = Eacc[mt][nt][i];
                *(unsigned short*)(Eh + eoff(r, t)) = (unsigned short)pk2(v, v);
            }

    // ================= Stage 2: S = E @ W  (hi-only) =================
    f32x4 Sacc[2][4];
    #pragma unroll
    for (int mt = 0; mt < 2; ++mt)
        #pragma unroll
        for (int nt = 0; nt < 4; ++nt)
            Sacc[mt][nt] = (f32x4){0.f, 0.f, 0.f, 0.f};

    const float* wsrc = W + xs_t;
    float ya[16];
    #pragma unroll
    for (int j = 0; j < 16; ++j) ya[j] = wsrc[(size_t)(xs_kh * 16 + j) * T_];

    #pragma unroll 2
    for (int c = 0; c < 8; ++c) {
        float yb2[16];
        if (c < 7) {
            #pragma unroll
            for (int j = 0; j < 16; ++j)
                yb2[j] = wsrc[(size_t)((c + 1) * 32 + xs_kh * 16 + j) * T_];
        }
        {
            char* bh = Bst[0] + xs_t * 72 + xs_kh * 32;
            #pragma unroll
            for (int q = 0; q < 4; ++q) {
                uint2 hp;
                hp.x = pk2(ya[q*4+0], ya[q*4+1]);
                hp.y = pk2(ya[q*4+2], ya[q*4+3]);
                *(uint2*)(bh + q * 8) = hp;
            }
        }
        __syncthreads();
        {
            bf16x8 Ahf[2], Bhf[4];
            #pragma unroll
            for (int mt = 0; mt < 2; ++mt)
                Ahf[mt] = ldE(Eh, rowW + mt * 16 + lane16, c * 32 + lg * 8);
            #pragma unroll
            for (int nt = 0; nt < 4; ++nt)
                Bhf[nt] = ld72(Bst[0], colW + nt * 16 + lane16, lg * 8);
            #pragma unroll
            for (int mt = 0; mt < 2; ++mt)
                #pragma unroll
                for (int nt = 0; nt < 4; ++nt)
                    Sacc[mt][nt] = MFMA16(Ahf[mt], Bhf[nt], Sacc[mt][nt], 0, 0, 0);
        }
        __syncthreads();
        if (c < 7) {
            #pragma unroll
            for (int j = 0; j < 16; ++j) ya[j] = yb2[j];
        }
    }

    // ============ row softmax over s (cross-wave) + blend, write hi/lo ============
    const float a_ = alpha[0];
    f32x4 pex[2][4];
    float pmv[2][4], psv[2][4];
    #pragma unroll
    for (int mt = 0; mt < 2; ++mt)
        #pragma unroll
        for (int i = 0; i < 4; ++i) {
            float m = fmaxf(fmaxf(Sacc[mt][0][i], Sacc[mt][1][i]),
                            fmaxf(Sacc[mt][2][i], Sacc[mt][3][i]));
            m = fmaxf(m, __shfl_xor(m, 1));
            m = fmaxf(m, __shfl_xor(m, 2));
            m = fmaxf(m, __shfl_xor(m, 4));
            m = fmaxf(m, __shfl_xor(m, 8));
            float s = 0.f;
            #pragma unroll
            for (int nt = 0; nt < 4; ++nt) {
                float p = __expf(Sacc[mt][nt][i] - m);
                pex[mt][nt][i] = p; s += p;
            }
            s += __shfl_xor(s, 1);
            s += __shfl_xor(s, 2);
            s += __shfl_xor(s, 4);
            s += __shfl_xor(s, 8);
            pmv[mt][i] = m; psv[mt][i] = s;
            if (lane16 == 0) {
                int r = rowW + mt * 16 + lg * 4 + i;
                redm[wn][r] = m; reds[wn][r] = s;
            }
        }
    __syncthreads();
    #pragma unroll
    for (int mt = 0; mt < 2; ++mt)
        #pragma unroll
        for (int i = 0; i < 4; ++i) {
            int r = rowW + mt * 16 + lg * 4 + i;
            float M = fmaxf(fmaxf(redm[0][r], redm[1][r]),
                            fmaxf(redm[2][r], redm[3][r]));
            float den = reds[0][r] * __expf(redm[0][r] - M)
                      + reds[1][r] * __expf(redm[1][r] - M)
                      + reds[2][r] * __expf(redm[2][r] - M)
                      + reds[3][r] * __expf(redm[3][r] - M);
            float sc = __expf(pmv[mt][i] - M) / den;
            #pragma unroll
            for (int nt = 0; nt < 4; ++nt) {
                float f = a_ + (1.f - a_) * pex[mt][nt][i] * sc;
                float v = Eacc[mt][nt][i] * f;
                int t = colW + nt * 16 + lane16;
                unsigned short h = (unsigned short)pk2(v, v);
                float hf = __uint_as_float((unsigned)h << 16);
                unsigned short l = (unsigned short)pk2(v - hf, v - hf);
                *(unsigned short*)(Eh + eoff(r, t)) = h;
                *(unsigned short*)(El + eoff(r, t)) = l;
            }
        }
    __syncthreads();

    // ================= Stage 3: Y = blended @ W2 + bias (3-term) =================
    f32x4 Yacc[2][2];
    #pragma unroll
    for (int mt = 0; mt < 2; ++mt)
        #pragma unroll
        for (int nt = 0; nt < 2; ++nt)
            Yacc[mt][nt] = (f32x4){0.f, 0.f, 0.f, 0.f};

    const int zs = tid & 127;   // s2 row
    const int zq = tid >> 7;    // 0..3 (k-quarter)
    const float* zsrc = W2 + zs;
    float za[8];
    #pragma unroll
    for (int j = 0; j < 8; ++j) za[j] = zsrc[(size_t)(zq * 8 + j) * O2_];

    #pragma unroll 2
    for (int c = 0; c < 8; ++c) {
        float zb2[8];
        if (c < 7) {
            #pragma unroll
            for (int j = 0; j < 8; ++j)
                zb2[j] = zsrc[(size_t)((c + 1) * 32 + zq * 8 + j) * O2_];
        }
        {
            char* bh = Bst[0] + zs * 72 + zq * 16;
            char* bl = Bst[1] + zs * 72 + zq * 16;
            uint2 hp, lp;
            split4(za[0], za[1], za[2], za[3], hp, lp);
            *(uint2*)bh = hp; *(uint2*)bl = lp;
            split4(za[4], za[5], za[6], za[7], hp, lp);
            *(uint2*)(bh + 8) = hp; *(uint2*)(bl + 8) = lp;
        }
        __syncthreads();
        {
            bf16x8 Ahf[2], Alf[2], Bhf[2], Blf[2];
            #pragma unroll
            for (int mt = 0; mt < 2; ++mt) {
                int r = rowW + mt * 16 + lane16;
                Ahf[mt] = ldE(Eh, r, c * 32 + lg * 8);
                Alf[mt] = ldE(El, r, c * 32 + lg * 8);
            }
            #pragma unroll
            for (int nt = 0; nt < 2; ++nt) {
                int n = wn * 32 + nt * 16 + lane16;
                Bhf[nt] = ld72(Bst[0], n, lg * 8);
                Blf[nt] = ld72(Bst[1], n, lg * 8);
            }
            #pragma unroll
            for (int mt = 0; mt < 2; ++mt)
                #pragma unroll
                for (int nt = 0; nt < 2; ++nt) {
                    Yacc[mt][nt] = MFMA16(Ahf[mt], Bhf[nt], Yacc[mt][nt], 0, 0, 0);
                    Yacc[mt][nt] = MFMA16(Ahf[mt], Blf[nt], Yacc[mt][nt], 0, 0, 0);
                    Yacc[mt][nt] = MFMA16(Alf[mt], Bhf[nt], Yacc[mt][nt], 0, 0, 0);
                }
        }
        __syncthreads();
        if (c < 7) {
            #pragma unroll
            for (int j = 0; j < 8; ++j) za[j] = zb2[j];
        }
    }

    // epilogue: + bias, store pre-softmax Y
    #pragma unroll
    for (int mt = 0; mt < 2; ++mt)
        #pragma unroll
        for (int nt = 0; nt < 2; ++nt)
            #pragma unroll
            for (int i = 0; i < 4; ++i) {
                int o  = obase + rowW + mt * 16 + lg * 4 + i;
                int s2 = wn * 32 + nt * 16 + lane16;
                out[((size_t)b * O1_ + o) * O2_ + s2] =
                    Yacc[mt][nt][i] + bias[(size_t)o * O2_ + s2];
            }
}

// in-place softmax over axis 1 (O1); one block per batch, 2 o-halves
__global__ __launch_bounds__(256) void softmax_o1(float* __restrict__ out)
{
    __shared__ float sm[2][128], ss[2][128];
    const int b  = blockIdx.x;
    const int s2 = threadIdx.x & 127;
    const int oh = threadIdx.x >> 7;
    float* p = out + (size_t)b * (O1_ * O2_) + s2;
    float m = -INFINITY, s = 0.f;
    #pragma unroll 4
    for (int o = oh * 128; o < oh * 128 + 128; ++o) {
        float v = p[(size_t)o * O2_];
        float mn = fmaxf(m, v);
        s = s * __expf(m - mn) + __expf(v - mn);
        m = mn;
    }
    sm[oh][s2] = m; ss[oh][s2] = s;
    __syncthreads();
    float M = fmaxf(sm[0][s2], sm[1][s2]);
    float S = ss[0][s2] * __expf(sm[0][s2] - M) + ss[1][s2] * __expf(sm[1][s2] - M);
    float inv = 1.f / S;
    #pragma unroll 4
    for (int o = oh * 128; o < oh * 128 + 128; ++o) {
        float v = p[(size_t)o * O2_];
        p[(size_t)o * O2_] = __expf(v - M) * inv;
    }
}

extern "C" void kernel_launch(void* const* d_in, const int* in_sizes, int n_in,
                              void* d_out, int out_size, void* d_ws, size_t ws_size,
                              hipStream_t stream)
{
    const float* x     = (const float*)d_in[0];
    const float* W1    = (const float*)d_in[1];
    const float* W     = (const float*)d_in[2];
    const float* W2    = (const float*)d_in[3];
    const float* alpha = (const float*)d_in[4];
    const float* bias  = (const float*)d_in[5];
    float* out = (float*)d_out;

    dim3 grid(O1_ / 64, B_);
    tabl_mfma<<<grid, 512, 0, stream>>>(x, W1, W, W2, alpha, bias, out);
    softmax_o1<<<B_, 256, 0, stream>>>(out);
}